// Round 1
// baseline (1287.115 us; speedup 1.0000x reference)
//
#include <hip/hip_runtime.h>
#include <hip/hip_bf16.h>
#include <math.h>

typedef __bf16 bf16_t;
typedef __bf16 bf16x8 __attribute__((ext_vector_type(8)));
typedef float f32x4 __attribute__((ext_vector_type(4)));

#define DIM 512

static __device__ __forceinline__ bf16_t f2bf(float x) { return (bf16_t)x; }

// ---------------- weight transpose+cast: Wt[z][n][k] = W_z[k][n] ----------------
__global__ void wt_kernel(const float* __restrict__ W0, const float* __restrict__ W1,
                          const float* __restrict__ W2, const float* __restrict__ W3,
                          const float* __restrict__ W4, const float* __restrict__ W5,
                          bf16_t* __restrict__ Wt)
{
    __shared__ float tile[32][33];
    const float* W;
    switch (blockIdx.z) {
        case 0: W = W0; break; case 1: W = W1; break; case 2: W = W2; break;
        case 3: W = W3; break; case 4: W = W4; break; default: W = W5; break;
    }
    const int tx = threadIdx.x, ty = threadIdx.y;
    const int n0 = blockIdx.x * 32, k0 = blockIdx.y * 32;
    #pragma unroll
    for (int r = 0; r < 4; ++r)
        tile[ty + 8*r][tx] = W[(size_t)(k0 + ty + 8*r) * DIM + n0 + tx];
    __syncthreads();
    bf16_t* Wtz = Wt + (size_t)blockIdx.z * DIM * DIM;
    #pragma unroll
    for (int r = 0; r < 4; ++r)
        Wtz[(size_t)(n0 + ty + 8*r) * DIM + k0 + tx] = f2bf(tile[tx][ty + 8*r]);
}

// ---------------- projection GEMM: C[M,512] = A[M,512](f32) @ Wt^T + bias ------
// Wt is [n][k] bf16 (pre-transposed). VOUT=0: C row-major bf16 [M][512].
// VOUT=1: transposed-V output Vt[b][n][t] with row stride TKP (b = m/TT, t = m%TT).
template<int VOUT, int TT, int TKP>
__global__ __launch_bounds__(256, 2)
void proj_gemm(const float* __restrict__ A, const bf16_t* __restrict__ Wt,
               const float* __restrict__ bias, bf16_t* __restrict__ C)
{
    __shared__ __align__(16) bf16_t a_lds[128 * 40];
    __shared__ __align__(16) bf16_t w_lds[128 * 40];
    const int tid = threadIdx.x;
    const int wv = tid >> 6, lane = tid & 63, l15 = lane & 15, l4 = lane >> 4;
    const int mBase = blockIdx.x * 128, nBase = blockIdx.y * 128;
    const int wr = wv >> 1, wc = wv & 1;
    const int srow = tid >> 1, shalf = tid & 1;

    const float*  ap = A  + (size_t)(mBase + srow) * DIM + shalf * 16;
    const bf16_t* wp = Wt + (size_t)(nBase + srow) * DIM + shalf * 16;
    bf16_t* a_dst = &a_lds[srow * 40 + shalf * 16];
    bf16_t* w_dst = &w_lds[srow * 40 + shalf * 16];

    f32x4 acc[4][4];
    #pragma unroll
    for (int f = 0; f < 4; ++f)
        #pragma unroll
        for (int g = 0; g < 4; ++g) acc[f][g] = (f32x4){0.f, 0.f, 0.f, 0.f};

    for (int kk = 0; kk < 16; ++kk) {
        const float* a_src = ap + kk * 32;
        f32x4 fa0 = *(const f32x4*)(a_src + 0);
        f32x4 fa1 = *(const f32x4*)(a_src + 4);
        f32x4 fa2 = *(const f32x4*)(a_src + 8);
        f32x4 fa3 = *(const f32x4*)(a_src + 12);
        bf16x8 wv0 = *(const bf16x8*)(wp + kk * 32 + 0);
        bf16x8 wv1 = *(const bf16x8*)(wp + kk * 32 + 8);
        bf16x8 s0, s1;
        #pragma unroll
        for (int u = 0; u < 4; ++u) {
            s0[u]     = f2bf(fa0[u]);
            s0[4 + u] = f2bf(fa1[u]);
            s1[u]     = f2bf(fa2[u]);
            s1[4 + u] = f2bf(fa3[u]);
        }
        *(bf16x8*)(a_dst)     = s0;
        *(bf16x8*)(a_dst + 8) = s1;
        *(bf16x8*)(w_dst)     = wv0;
        *(bf16x8*)(w_dst + 8) = wv1;
        __syncthreads();

        bf16x8 af[4], bfr[4];
        #pragma unroll
        for (int f = 0; f < 4; ++f)
            af[f] = *(const bf16x8*)&a_lds[(wr * 64 + f * 16 + l15) * 40 + l4 * 8];
        #pragma unroll
        for (int g = 0; g < 4; ++g)
            bfr[g] = *(const bf16x8*)&w_lds[(wc * 64 + g * 16 + l15) * 40 + l4 * 8];
        #pragma unroll
        for (int f = 0; f < 4; ++f)
            #pragma unroll
            for (int g = 0; g < 4; ++g)
                acc[f][g] = __builtin_amdgcn_mfma_f32_16x16x32_bf16(af[f], bfr[g], acc[f][g], 0, 0, 0);
        __syncthreads();
    }

    // epilogue: + bias, convert, store
    #pragma unroll
    for (int g = 0; g < 4; ++g) {
        const int n = nBase + wc * 64 + g * 16 + l15;
        const float bv = bias[n];
        #pragma unroll
        for (int f = 0; f < 4; ++f) {
            #pragma unroll
            for (int i = 0; i < 4; ++i) {
                float v = acc[f][g][i] + bv;
                int m = mBase + wr * 64 + f * 16 + 4 * l4 + i;
                if (VOUT == 0) {
                    C[(size_t)m * DIM + n] = f2bf(v);
                } else {
                    int bb = m / TT;
                    int t  = m - bb * TT;
                    C[(size_t)bb * DIM * TKP + (size_t)n * TKP + t] = f2bf(v);
                }
            }
        }
    }
}

// ---------------- fused banded cross-attention ----------------
// MODE 0 (e2f): q = eeg t, k = fnirs j, valid iff j in [t/20+20, t/20+80]
// MODE 1 (f2e): q = fnirs j, k = eeg t, valid iff j in [t/20+20, t/20+80]
// Keys >= TK (padding) -> -inf (excluded); real-masked -> -1e9 (matches reference,
// and makes empty rows reproduce the reference's uniform-softmax behavior).
template<int TQ, int TK, int MODE>
static __device__ __forceinline__ float score_val(int q, int k, float raw) {
    if (k >= TK) return -INFINITY;
    const int t = (MODE == 0) ? q : k;
    const int j = (MODE == 0) ? k : q;
    const int j0 = t / 20;
    const bool valid = (j >= j0 + 20) && (j <= j0 + 80);
    return valid ? raw * 0.04419417382415922f : -1e9f;
}

template<int TQ, int TK, int TKP, int MODE>
__global__ __launch_bounds__(256, 2)
void attn_kernel(const bf16_t* __restrict__ Qsrc, const bf16_t* __restrict__ Ksrc,
                 const bf16_t* __restrict__ Vt, float* __restrict__ Out)
{
    constexpr int NKT = TKP / 32;
    __shared__ __align__(16) bf16_t p_lds[4][16][40];

    const int b = blockIdx.y;
    const int tid = threadIdx.x;
    const int wv = tid >> 6, lane = tid & 63, l15 = lane & 15, l4 = lane >> 4;
    const int qbase = blockIdx.x * 64 + wv * 16;

    const bf16_t* Qb = Qsrc + (size_t)b * TQ * DIM;
    const bf16_t* Kb = Ksrc + (size_t)b * TK * DIM;
    const bf16_t* Vb = Vt   + (size_t)b * DIM * TKP;

    // Q fragments: 16 q-rows x 512 d, held in registers (64 VGPRs)
    bf16x8 q[16];
    {
        int qr = qbase + l15; if (qr >= TQ) qr = TQ - 1;
        const bf16_t* qp = Qb + (size_t)qr * DIM + l4 * 8;
        #pragma unroll
        for (int c = 0; c < 16; ++c) q[c] = *(const bf16x8*)(qp + c * 32);
    }

    // ---- pass 1: row max ----
    float mrow[4] = {-INFINITY, -INFINITY, -INFINITY, -INFINITY};
    for (int kt = 0; kt < NKT; ++kt) {
        #pragma unroll
        for (int h = 0; h < 2; ++h) {
            const int kc0 = kt * 32 + h * 16;
            int kr = kc0 + l15; int krl = (kr < TK) ? kr : (TK - 1);
            const bf16_t* kp = Kb + (size_t)krl * DIM + l4 * 8;
            f32x4 acc = (f32x4){0.f, 0.f, 0.f, 0.f};
            #pragma unroll
            for (int c = 0; c < 16; ++c) {
                bf16x8 kf = *(const bf16x8*)(kp + c * 32);
                acc = __builtin_amdgcn_mfma_f32_16x16x32_bf16(q[c], kf, acc, 0, 0, 0);
            }
            #pragma unroll
            for (int i = 0; i < 4; ++i) {
                float s = score_val<TQ, TK, MODE>(qbase + 4 * l4 + i, kc0 + l15, acc[i]);
                mrow[i] = fmaxf(mrow[i], s);
            }
        }
    }
    #pragma unroll
    for (int i = 0; i < 4; ++i) {
        mrow[i] = fmaxf(mrow[i], __shfl_xor(mrow[i], 1, 16));
        mrow[i] = fmaxf(mrow[i], __shfl_xor(mrow[i], 2, 16));
        mrow[i] = fmaxf(mrow[i], __shfl_xor(mrow[i], 4, 16));
        mrow[i] = fmaxf(mrow[i], __shfl_xor(mrow[i], 8, 16));
    }

    // ---- pass 2: exp, P->LDS->A-frag, PV ----
    float lsum[4] = {0.f, 0.f, 0.f, 0.f};
    f32x4 o[32];
    #pragma unroll
    for (int dc = 0; dc < 32; ++dc) o[dc] = (f32x4){0.f, 0.f, 0.f, 0.f};

    for (int kt = 0; kt < NKT; ++kt) {
        #pragma unroll
        for (int h = 0; h < 2; ++h) {
            const int kc0 = kt * 32 + h * 16;
            int kr = kc0 + l15; int krl = (kr < TK) ? kr : (TK - 1);
            const bf16_t* kp = Kb + (size_t)krl * DIM + l4 * 8;
            f32x4 acc = (f32x4){0.f, 0.f, 0.f, 0.f};
            #pragma unroll
            for (int c = 0; c < 16; ++c) {
                bf16x8 kf = *(const bf16x8*)(kp + c * 32);
                acc = __builtin_amdgcn_mfma_f32_16x16x32_bf16(q[c], kf, acc, 0, 0, 0);
            }
            #pragma unroll
            for (int i = 0; i < 4; ++i) {
                float s = score_val<TQ, TK, MODE>(qbase + 4 * l4 + i, kc0 + l15, acc[i]);
                float e = __expf(s - mrow[i]);
                lsum[i] += e;
                p_lds[wv][4 * l4 + i][h * 16 + l15] = f2bf(e);
            }
        }
        __builtin_amdgcn_sched_barrier(0);  // keep P writes before P read (same-wave LDS exchange)
        bf16x8 pa = *(const bf16x8*)&p_lds[wv][l15][l4 * 8];
        #pragma unroll
        for (int dc = 0; dc < 32; ++dc) {
            bf16x8 vvf = *(const bf16x8*)(Vb + (size_t)(dc * 16 + l15) * TKP + kt * 32 + l4 * 8);
            o[dc] = __builtin_amdgcn_mfma_f32_16x16x32_bf16(pa, vvf, o[dc], 0, 0, 0);
        }
    }

    #pragma unroll
    for (int i = 0; i < 4; ++i) {
        lsum[i] += __shfl_xor(lsum[i], 1, 16);
        lsum[i] += __shfl_xor(lsum[i], 2, 16);
        lsum[i] += __shfl_xor(lsum[i], 4, 16);
        lsum[i] += __shfl_xor(lsum[i], 8, 16);
        lsum[i] = 1.0f / lsum[i];
    }

    float* Ob = Out + (size_t)b * TQ * DIM;
    #pragma unroll
    for (int i = 0; i < 4; ++i) {
        const int qr = qbase + 4 * l4 + i;
        if (qr < TQ) {
            #pragma unroll
            for (int dc = 0; dc < 32; ++dc)
                Ob[(size_t)qr * DIM + dc * 16 + l15] = o[dc][i] * lsum[i];
        }
    }
}

// ---------------- host launch ----------------
extern "C" void kernel_launch(void* const* d_in, const int* in_sizes, int n_in,
                              void* d_out, int out_size, void* d_ws, size_t ws_size,
                              hipStream_t stream)
{
    (void)in_sizes; (void)n_in; (void)out_size; (void)ws_size;
    const float* eeg   = (const float*)d_in[0];
    const float* fnirs = (const float*)d_in[1];
    const float* Wqe = (const float*)d_in[2];  const float* bqe = (const float*)d_in[3];
    const float* Wke = (const float*)d_in[4];  const float* bke = (const float*)d_in[5];
    const float* Wve = (const float*)d_in[6];  const float* bve = (const float*)d_in[7];
    const float* Wqf = (const float*)d_in[8];  const float* bqf = (const float*)d_in[9];
    const float* Wkf = (const float*)d_in[10]; const float* bkf = (const float*)d_in[11];
    const float* Wvf = (const float*)d_in[12]; const float* bvf = (const float*)d_in[13];

    char* ws = (char*)d_ws;
    // workspace layout (bytes); total = 288,358,400
    bf16_t* Wt   = (bf16_t*)(ws);                      // 6*512*512*2      = 3,145,728
    bf16_t* Qe   = (bf16_t*)(ws + 3145728);            // 76800*512*2     = 78,643,200
    bf16_t* Ke   = (bf16_t*)(ws + 81788928);           // 78,643,200
    bf16_t* Qf   = (bf16_t*)(ws + 160432128);          // 15360*512*2     = 15,728,640
    bf16_t* Kf   = (bf16_t*)(ws + 176160768);          // 15,728,640
    bf16_t* Ve_t = (bf16_t*)(ws + 191889408);          // 128*512*608*2   = 79,691,776
    bf16_t* Vf_t = (bf16_t*)(ws + 271581184);          // 128*512*128*2   = 16,777,216

    wt_kernel<<<dim3(16, 16, 6), dim3(32, 8), 0, stream>>>(Wqe, Wke, Wve, Wqf, Wkf, Wvf, Wt);

    // eeg projections: M = 128*600 = 76800 -> grid (600, 4)
    proj_gemm<0, 600, 608><<<dim3(600, 4), 256, 0, stream>>>(eeg, Wt + 0 * 262144, bqe, Qe);
    proj_gemm<0, 600, 608><<<dim3(600, 4), 256, 0, stream>>>(eeg, Wt + 1 * 262144, bke, Ke);
    proj_gemm<1, 600, 608><<<dim3(600, 4), 256, 0, stream>>>(eeg, Wt + 2 * 262144, bve, Ve_t);
    // fnirs projections: M = 128*120 = 15360 -> grid (120, 4)
    proj_gemm<0, 120, 128><<<dim3(120, 4), 256, 0, stream>>>(fnirs, Wt + 3 * 262144, bqf, Qf);
    proj_gemm<0, 120, 128><<<dim3(120, 4), 256, 0, stream>>>(fnirs, Wt + 4 * 262144, bkf, Kf);
    proj_gemm<1, 120, 128><<<dim3(120, 4), 256, 0, stream>>>(fnirs, Wt + 5 * 262144, bvf, Vf_t);

    float* out_eeg   = (float*)d_out;                              // aligned_eeg  [128][120][512]
    float* out_fnirs = (float*)d_out + (size_t)128 * 120 * 512;    // aligned_fnirs[128][600][512]

    // e2f: Q = Qe (600), K/V = fnirs side (120 keys, TKP=128)
    attn_kernel<600, 120, 128, 0><<<dim3(10, 128), 256, 0, stream>>>(Qe, Kf, Vf_t, out_fnirs);
    // f2e: Q = Qf (120), K/V = eeg side (600 keys, TKP=608)
    attn_kernel<120, 600, 608, 1><<<dim3(2, 128), 256, 0, stream>>>(Qf, Ke, Ve_t, out_eeg);
}

// Round 2
// 761.233 us; speedup vs baseline: 1.6908x; 1.6908x over previous
//
#include <hip/hip_runtime.h>
#include <hip/hip_bf16.h>
#include <math.h>

typedef __bf16 bf16_t;
typedef __bf16 bf16x8 __attribute__((ext_vector_type(8)));
typedef float f32x4 __attribute__((ext_vector_type(4)));

#define DIM 512
#define SCALE 0.04419417382415922f

static __device__ __forceinline__ bf16_t f2bf(float x) { return (bf16_t)x; }
static __device__ __forceinline__ int imin(int a, int b) { return a < b ? a : b; }

// ---------------- weight transpose+cast: Wt[z][n][k] = W_z[k][n] ----------------
__global__ void wt_kernel(const float* __restrict__ W0, const float* __restrict__ W1,
                          const float* __restrict__ W2, const float* __restrict__ W3,
                          const float* __restrict__ W4, const float* __restrict__ W5,
                          bf16_t* __restrict__ Wt)
{
    __shared__ float tile[32][33];
    const float* W;
    switch (blockIdx.z) {
        case 0: W = W0; break; case 1: W = W1; break; case 2: W = W2; break;
        case 3: W = W3; break; case 4: W = W4; break; default: W = W5; break;
    }
    const int tx = threadIdx.x, ty = threadIdx.y;
    const int n0 = blockIdx.x * 32, k0 = blockIdx.y * 32;
    #pragma unroll
    for (int r = 0; r < 4; ++r)
        tile[ty + 8*r][tx] = W[(size_t)(k0 + ty + 8*r) * DIM + n0 + tx];
    __syncthreads();
    bf16_t* Wtz = Wt + (size_t)blockIdx.z * DIM * DIM;
    #pragma unroll
    for (int r = 0; r < 4; ++r)
        Wtz[(size_t)(n0 + ty + 8*r) * DIM + k0 + tx] = f2bf(tile[tx][ty + 8*r]);
}

// ---------------- projection GEMM: C[M,512] = A[M,512](f32) @ Wt^T + bias ------
// 1-D grid of TT*4 blocks, decoded so the 4 col-blocks sharing an A row-tile are
// consecutive within one XCD's stride-8 dispatch stream (A fetched once per XCD).
template<int VOUT, int TT, int TKP>
__global__ __launch_bounds__(256, 2)
void proj_gemm(const float* __restrict__ A, const bf16_t* __restrict__ Wt,
               const float* __restrict__ bias, bf16_t* __restrict__ C)
{
    __shared__ __align__(16) bf16_t a_lds[128 * 40];
    __shared__ __align__(16) bf16_t w_lds[128 * 40];
    const int g = blockIdx.x;
    const int rowt = (g >> 5) * 8 + (g & 7);   // TT row-tiles (TT % 8 == 0)
    const int colt = (g >> 3) & 3;             // 4 col-tiles
    const int tid = threadIdx.x;
    const int wv = tid >> 6, lane = tid & 63, l15 = lane & 15, l4 = lane >> 4;
    const int mBase = rowt * 128, nBase = colt * 128;
    const int wr = wv >> 1, wc = wv & 1;
    const int srow = tid >> 1, shalf = tid & 1;

    const float*  ap = A  + (size_t)(mBase + srow) * DIM + shalf * 16;
    const bf16_t* wp = Wt + (size_t)(nBase + srow) * DIM + shalf * 16;
    bf16_t* a_dst = &a_lds[srow * 40 + shalf * 16];
    bf16_t* w_dst = &w_lds[srow * 40 + shalf * 16];

    f32x4 acc[4][4];
    #pragma unroll
    for (int f = 0; f < 4; ++f)
        #pragma unroll
        for (int gg = 0; gg < 4; ++gg) acc[f][gg] = (f32x4){0.f, 0.f, 0.f, 0.f};

    for (int kk = 0; kk < 16; ++kk) {
        const float* a_src = ap + kk * 32;
        f32x4 fa0 = *(const f32x4*)(a_src + 0);
        f32x4 fa1 = *(const f32x4*)(a_src + 4);
        f32x4 fa2 = *(const f32x4*)(a_src + 8);
        f32x4 fa3 = *(const f32x4*)(a_src + 12);
        bf16x8 wv0 = *(const bf16x8*)(wp + kk * 32 + 0);
        bf16x8 wv1 = *(const bf16x8*)(wp + kk * 32 + 8);
        bf16x8 s0, s1;
        #pragma unroll
        for (int u = 0; u < 4; ++u) {
            s0[u]     = f2bf(fa0[u]);
            s0[4 + u] = f2bf(fa1[u]);
            s1[u]     = f2bf(fa2[u]);
            s1[4 + u] = f2bf(fa3[u]);
        }
        *(bf16x8*)(a_dst)     = s0;
        *(bf16x8*)(a_dst + 8) = s1;
        *(bf16x8*)(w_dst)     = wv0;
        *(bf16x8*)(w_dst + 8) = wv1;
        __syncthreads();

        bf16x8 af[4], bfr[4];
        #pragma unroll
        for (int f = 0; f < 4; ++f)
            af[f] = *(const bf16x8*)&a_lds[(wr * 64 + f * 16 + l15) * 40 + l4 * 8];
        #pragma unroll
        for (int gg = 0; gg < 4; ++gg)
            bfr[gg] = *(const bf16x8*)&w_lds[(wc * 64 + gg * 16 + l15) * 40 + l4 * 8];
        #pragma unroll
        for (int f = 0; f < 4; ++f)
            #pragma unroll
            for (int gg = 0; gg < 4; ++gg)
                acc[f][gg] = __builtin_amdgcn_mfma_f32_16x16x32_bf16(af[f], bfr[gg], acc[f][gg], 0, 0, 0);
        __syncthreads();
    }

    #pragma unroll
    for (int gg = 0; gg < 4; ++gg) {
        const int n = nBase + wc * 64 + gg * 16 + l15;
        const float bv = bias[n];
        #pragma unroll
        for (int f = 0; f < 4; ++f) {
            #pragma unroll
            for (int i = 0; i < 4; ++i) {
                float v = acc[f][gg][i] + bv;
                int m = mBase + wr * 64 + f * 16 + 4 * l4 + i;
                if (VOUT == 0) {
                    C[(size_t)m * DIM + n] = f2bf(v);
                } else {
                    int bb = m / TT;
                    int t  = m - bb * TT;
                    C[(size_t)bb * DIM * TKP + (size_t)n * TKP + t] = f2bf(v);
                }
            }
        }
    }
}

// ---------------- e2f attention (Q=eeg 600 rows, K/V=fnirs 120 keys) ----------
// Band: for q-row t, valid keys j in [t/20+20, t/20+80] (<= 62 wide, always
// nonempty). K0 = chunk-aligned band start; 5 x 16-key chunks always cover it.
__global__ __launch_bounds__(256, 4)
void attn_e2f(const bf16_t* __restrict__ Q, const bf16_t* __restrict__ K,
              const bf16_t* __restrict__ Vt, float* __restrict__ Out)
{
    __shared__ __align__(16) bf16_t p_lds[4][16][104];   // 96 cols + pad
    const int b = blockIdx.x, qb = blockIdx.y;
    const int tid = threadIdx.x;
    const int wv = tid >> 6, lane = tid & 63, l15 = lane & 15, l4 = lane >> 4;
    const int qbase = qb * 64 + wv * 16;
    const int K0 = (((qbase / 20) + 20) >> 4) << 4;      // 16, 32 or 48

    const bf16_t* Qb = Q  + (size_t)b * 600 * DIM;
    const bf16_t* Kb = K  + (size_t)b * 120 * DIM;
    const bf16_t* Vb = Vt + (size_t)b * DIM * 128;

    // Q fragments (rows qbase..qbase+15, clamped)
    const int qr = imin(qbase + l15, 599);
    const bf16_t* qp = Qb + (size_t)qr * DIM + l4 * 8;
    bf16x8 q[16];
    #pragma unroll
    for (int c = 0; c < 16; ++c) q[c] = *(const bf16x8*)(qp + c * 32);

    // K row byte-offsets (5 chunks of 16 keys)
    int koffs[5];
    #pragma unroll
    for (int ch = 0; ch < 5; ++ch)
        koffs[ch] = imin(K0 + ch * 16 + l15, 119) * (DIM * 2);
    const char* KbL = (const char*)(Kb + l4 * 8);

    // QK^T: 5 independent accumulation chains
    f32x4 acc[5];
    #pragma unroll
    for (int ch = 0; ch < 5; ++ch) acc[ch] = (f32x4){0.f, 0.f, 0.f, 0.f};
    #pragma unroll
    for (int c = 0; c < 16; ++c) {
        #pragma unroll
        for (int ch = 0; ch < 5; ++ch) {
            bf16x8 kf = *(const bf16x8*)(KbL + koffs[ch] + c * 64);
            acc[ch] = __builtin_amdgcn_mfma_f32_16x16x32_bf16(q[c], kf, acc[ch], 0, 0, 0);
        }
    }

    // mask + scale + row max (band always nonempty -> -inf for invalid is exact)
    float m[4] = {-INFINITY, -INFINITY, -INFINITY, -INFINITY};
    #pragma unroll
    for (int ch = 0; ch < 5; ++ch) {
        #pragma unroll
        for (int i = 0; i < 4; ++i) {
            const int t = qbase + 4 * l4 + i;
            const int k = K0 + ch * 16 + l15;
            const int j0 = t / 20;
            const bool valid = (k < 120) && (k >= j0 + 20) && (k <= j0 + 80);
            float s = valid ? acc[ch][i] * SCALE : -INFINITY;
            acc[ch][i] = s;
            m[i] = fmaxf(m[i], s);
        }
    }
    #pragma unroll
    for (int i = 0; i < 4; ++i) {
        m[i] = fmaxf(m[i], __shfl_xor(m[i], 1, 16));
        m[i] = fmaxf(m[i], __shfl_xor(m[i], 2, 16));
        m[i] = fmaxf(m[i], __shfl_xor(m[i], 4, 16));
        m[i] = fmaxf(m[i], __shfl_xor(m[i], 8, 16));
    }

    // exp -> P (bf16) into LDS; zero-fill pad chunk (cols 80..95)
    float lsum[4] = {0.f, 0.f, 0.f, 0.f};
    #pragma unroll
    for (int ch = 0; ch < 5; ++ch) {
        #pragma unroll
        for (int i = 0; i < 4; ++i) {
            float e = __expf(acc[ch][i] - m[i]);
            lsum[i] += e;
            p_lds[wv][4 * l4 + i][ch * 16 + l15] = f2bf(e);
        }
    }
    #pragma unroll
    for (int i = 0; i < 4; ++i)
        p_lds[wv][4 * l4 + i][80 + l15] = f2bf(0.f);
    #pragma unroll
    for (int i = 0; i < 4; ++i) {
        lsum[i] += __shfl_xor(lsum[i], 1, 16);
        lsum[i] += __shfl_xor(lsum[i], 2, 16);
        lsum[i] += __shfl_xor(lsum[i], 4, 16);
        lsum[i] += __shfl_xor(lsum[i], 8, 16);
        lsum[i] = 1.0f / lsum[i];
    }
    __syncthreads();   // fence p_lds write -> read (and aligns waves)

    bf16x8 pa[3];
    #pragma unroll
    for (int kt = 0; kt < 3; ++kt)
        pa[kt] = *(const bf16x8*)&p_lds[wv][l15][kt * 32 + l4 * 8];
    int vb[3];
    #pragma unroll
    for (int kt = 0; kt < 3; ++kt) vb[kt] = imin(K0 + kt * 32, 96);  // P==0 where clamped

    float* Ob = Out + (size_t)b * 600 * DIM;
    #pragma unroll
    for (int dcg = 0; dcg < 8; ++dcg) {
        f32x4 o[4];
        #pragma unroll
        for (int u = 0; u < 4; ++u) o[u] = (f32x4){0.f, 0.f, 0.f, 0.f};
        #pragma unroll
        for (int u = 0; u < 4; ++u) {
            const bf16_t* vrow = Vb + (size_t)(dcg * 64 + u * 16 + l15) * 128 + l4 * 8;
            #pragma unroll
            for (int kt = 0; kt < 3; ++kt) {
                bf16x8 vf = *(const bf16x8*)(vrow + vb[kt]);
                o[u] = __builtin_amdgcn_mfma_f32_16x16x32_bf16(pa[kt], vf, o[u], 0, 0, 0);
            }
        }
        #pragma unroll
        for (int u = 0; u < 4; ++u) {
            #pragma unroll
            for (int i = 0; i < 4; ++i) {
                const int t = qbase + 4 * l4 + i;
                if (t < 600)
                    Ob[(size_t)t * DIM + (dcg * 4 + u) * 16 + l15] = o[u][i] * lsum[i];
            }
        }
    }
}

// ---------------- f2e attention (Q=fnirs 120 rows, K/V=eeg 600 keys) ----------
// 4 waves split the 608-padded key range (160 each); max/sum/PV-partials are
// combined through LDS. Real masked keys get -1e9 (reference semantics: empty
// rows -> uniform softmax over all 600 keys); pad keys >= 600 get -inf.
__global__ __launch_bounds__(256, 3)
void attn_f2e(const bf16_t* __restrict__ Q, const bf16_t* __restrict__ K,
              const bf16_t* __restrict__ Vt, float* __restrict__ Out)
{
    __shared__ __align__(16) bf16_t p_lds[4][16][168];   // 160 cols + pad
    __shared__ __align__(16) float o_lds[4][4][16][16];
    __shared__ float m_lds[4][16];
    __shared__ float l_lds[4][16];

    const int b = blockIdx.x, qt = blockIdx.y;
    const int tid = threadIdx.x;
    const int wv = tid >> 6, lane = tid & 63, l15 = lane & 15, l4 = lane >> 4;
    const int qbase = qt * 16;
    const int koff = wv * 160;

    const bf16_t* Qb = Q  + (size_t)b * 120 * DIM;
    const bf16_t* Kb = K  + (size_t)b * 600 * DIM;
    const bf16_t* Vb = Vt + (size_t)b * DIM * 608;

    const int qr = imin(qbase + l15, 119);
    const bf16_t* qp = Qb + (size_t)qr * DIM + l4 * 8;
    bf16x8 q[16];
    #pragma unroll
    for (int c = 0; c < 16; ++c) q[c] = *(const bf16x8*)(qp + c * 32);

    int koffs[10];
    #pragma unroll
    for (int ch = 0; ch < 10; ++ch)
        koffs[ch] = imin(koff + ch * 16 + l15, 599) * (DIM * 2);
    const char* KbL = (const char*)(Kb + l4 * 8);

    f32x4 acc[10];
    #pragma unroll
    for (int ch = 0; ch < 10; ++ch) acc[ch] = (f32x4){0.f, 0.f, 0.f, 0.f};
    #pragma unroll
    for (int c = 0; c < 16; ++c) {
        #pragma unroll
        for (int ch = 0; ch < 10; ++ch) {
            bf16x8 kf = *(const bf16x8*)(KbL + koffs[ch] + c * 64);
            acc[ch] = __builtin_amdgcn_mfma_f32_16x16x32_bf16(q[c], kf, acc[ch], 0, 0, 0);
        }
    }

    // mask + scale + wave-local max
    float m[4] = {-INFINITY, -INFINITY, -INFINITY, -INFINITY};
    #pragma unroll
    for (int ch = 0; ch < 10; ++ch) {
        #pragma unroll
        for (int i = 0; i < 4; ++i) {
            const int j = qbase + 4 * l4 + i;          // fnirs row
            const int k = koff + ch * 16 + l15;        // eeg key
            float s;
            if (k >= 600) {
                s = -INFINITY;
            } else {
                const int j0 = k / 20;
                s = (j >= j0 + 20 && j <= j0 + 80) ? acc[ch][i] * SCALE : -1e9f;
            }
            acc[ch][i] = s;
            m[i] = fmaxf(m[i], s);
        }
    }
    #pragma unroll
    for (int i = 0; i < 4; ++i) {
        m[i] = fmaxf(m[i], __shfl_xor(m[i], 1, 16));
        m[i] = fmaxf(m[i], __shfl_xor(m[i], 2, 16));
        m[i] = fmaxf(m[i], __shfl_xor(m[i], 4, 16));
        m[i] = fmaxf(m[i], __shfl_xor(m[i], 8, 16));
    }
    if (l15 == 0) {
        #pragma unroll
        for (int i = 0; i < 4; ++i) m_lds[wv][4 * l4 + i] = m[i];
    }
    __syncthreads();
    float mg[4];
    #pragma unroll
    for (int i = 0; i < 4; ++i) {
        const int rr = 4 * l4 + i;
        mg[i] = fmaxf(fmaxf(m_lds[0][rr], m_lds[1][rr]), fmaxf(m_lds[2][rr], m_lds[3][rr]));
    }

    float lsum[4] = {0.f, 0.f, 0.f, 0.f};
    #pragma unroll
    for (int ch = 0; ch < 10; ++ch) {
        #pragma unroll
        for (int i = 0; i < 4; ++i) {
            float e = __expf(acc[ch][i] - mg[i]);
            lsum[i] += e;
            p_lds[wv][4 * l4 + i][ch * 16 + l15] = f2bf(e);
        }
    }
    #pragma unroll
    for (int i = 0; i < 4; ++i) {
        lsum[i] += __shfl_xor(lsum[i], 1, 16);
        lsum[i] += __shfl_xor(lsum[i], 2, 16);
        lsum[i] += __shfl_xor(lsum[i], 4, 16);
        lsum[i] += __shfl_xor(lsum[i], 8, 16);
    }
    if (l15 == 0) {
        #pragma unroll
        for (int i = 0; i < 4; ++i) l_lds[wv][4 * l4 + i] = lsum[i];
    }
    __syncthreads();   // also fences p_lds writes -> reads below

    bf16x8 pa[5];
    #pragma unroll
    for (int kt = 0; kt < 5; ++kt)
        pa[kt] = *(const bf16x8*)&p_lds[wv][l15][kt * 32 + l4 * 8];
    int vb[5];
    #pragma unroll
    for (int kt = 0; kt < 5; ++kt) vb[kt] = imin(koff + kt * 32, 576);  // P==0 where clamped

    const int tu = tid >> 6, trow = (tid >> 2) & 15, tc0 = (tid & 3) * 4;
    const float linv = 1.0f / (l_lds[0][trow] + l_lds[1][trow] + l_lds[2][trow] + l_lds[3][trow]);
    float* Ob = Out + (size_t)b * 120 * DIM;
    const int orow = qbase + trow;

    for (int r = 0; r < 8; ++r) {
        f32x4 o[4];
        #pragma unroll
        for (int u = 0; u < 4; ++u) o[u] = (f32x4){0.f, 0.f, 0.f, 0.f};
        #pragma unroll
        for (int u = 0; u < 4; ++u) {
            const bf16_t* vrow = Vb + (size_t)((r * 4 + u) * 16 + l15) * 608 + l4 * 8;
            #pragma unroll
            for (int kt = 0; kt < 5; ++kt) {
                bf16x8 vf = *(const bf16x8*)(vrow + vb[kt]);
                o[u] = __builtin_amdgcn_mfma_f32_16x16x32_bf16(pa[kt], vf, o[u], 0, 0, 0);
            }
        }
        __syncthreads();   // previous round's o_lds fully consumed
        #pragma unroll
        for (int u = 0; u < 4; ++u)
            #pragma unroll
            for (int i = 0; i < 4; ++i)
                o_lds[wv][u][4 * l4 + i][l15] = o[u][i];
        __syncthreads();
        f32x4 s = *(const f32x4*)&o_lds[0][tu][trow][tc0];
        s += *(const f32x4*)&o_lds[1][tu][trow][tc0];
        s += *(const f32x4*)&o_lds[2][tu][trow][tc0];
        s += *(const f32x4*)&o_lds[3][tu][trow][tc0];
        if (orow < 120) {
            s *= linv;
            *(f32x4*)&Ob[(size_t)orow * DIM + r * 64 + tu * 16 + tc0] = s;
        }
    }
}

// ---------------- host launch ----------------
extern "C" void kernel_launch(void* const* d_in, const int* in_sizes, int n_in,
                              void* d_out, int out_size, void* d_ws, size_t ws_size,
                              hipStream_t stream)
{
    (void)in_sizes; (void)n_in; (void)out_size; (void)ws_size;
    const float* eeg   = (const float*)d_in[0];
    const float* fnirs = (const float*)d_in[1];
    const float* Wqe = (const float*)d_in[2];  const float* bqe = (const float*)d_in[3];
    const float* Wke = (const float*)d_in[4];  const float* bke = (const float*)d_in[5];
    const float* Wve = (const float*)d_in[6];  const float* bve = (const float*)d_in[7];
    const float* Wqf = (const float*)d_in[8];  const float* bqf = (const float*)d_in[9];
    const float* Wkf = (const float*)d_in[10]; const float* bkf = (const float*)d_in[11];
    const float* Wvf = (const float*)d_in[12]; const float* bvf = (const float*)d_in[13];

    char* ws = (char*)d_ws;
    bf16_t* Wt   = (bf16_t*)(ws);                      // 3,145,728 B
    bf16_t* Qe   = (bf16_t*)(ws + 3145728);            // 78,643,200
    bf16_t* Ke   = (bf16_t*)(ws + 81788928);           // 78,643,200
    bf16_t* Qf   = (bf16_t*)(ws + 160432128);          // 15,728,640
    bf16_t* Kf   = (bf16_t*)(ws + 176160768);          // 15,728,640
    bf16_t* Ve_t = (bf16_t*)(ws + 191889408);          // 79,691,776
    bf16_t* Vf_t = (bf16_t*)(ws + 271581184);          // 16,777,216

    wt_kernel<<<dim3(16, 16, 6), dim3(32, 8), 0, stream>>>(Wqe, Wke, Wve, Wqf, Wkf, Wvf, Wt);

    // eeg projections: 600 row-tiles x 4 col-tiles
    proj_gemm<0, 600, 608><<<2400, 256, 0, stream>>>(eeg, Wt + 0 * 262144, bqe, Qe);
    proj_gemm<0, 600, 608><<<2400, 256, 0, stream>>>(eeg, Wt + 1 * 262144, bke, Ke);
    proj_gemm<1, 600, 608><<<2400, 256, 0, stream>>>(eeg, Wt + 2 * 262144, bve, Ve_t);
    // fnirs projections: 120 row-tiles x 4 col-tiles
    proj_gemm<0, 120, 128><<<480, 256, 0, stream>>>(fnirs, Wt + 3 * 262144, bqf, Qf);
    proj_gemm<0, 120, 128><<<480, 256, 0, stream>>>(fnirs, Wt + 4 * 262144, bkf, Kf);
    proj_gemm<1, 120, 128><<<480, 256, 0, stream>>>(fnirs, Wt + 5 * 262144, bvf, Vf_t);

    float* out_eeg   = (float*)d_out;                              // [128][120][512]
    float* out_fnirs = (float*)d_out + (size_t)128 * 120 * 512;    // [128][600][512]

    attn_e2f<<<dim3(128, 10), 256, 0, stream>>>(Qe, Kf, Vf_t, out_fnirs);
    attn_f2e<<<dim3(128, 8),  256, 0, stream>>>(Qf, Ke, Ve_t, out_eeg);
}

// Round 3
// 674.169 us; speedup vs baseline: 1.9092x; 1.1291x over previous
//
#include <hip/hip_runtime.h>
#include <hip/hip_bf16.h>
#include <math.h>

typedef __bf16 bf16_t;
typedef __bf16 bf16x8 __attribute__((ext_vector_type(8)));
typedef float f32x4 __attribute__((ext_vector_type(4)));

#define DIM 512
#define SCALE 0.04419417382415922f

static __device__ __forceinline__ bf16_t f2bf(float x) { return (bf16_t)x; }
static __device__ __forceinline__ int imin(int a, int b) { return a < b ? a : b; }

// async global->LDS, 16 B per lane (dest = wave-uniform base + lane*16)
static __device__ __forceinline__ void gload16(const void* g, void* l) {
    __builtin_amdgcn_global_load_lds((const __attribute__((address_space(1))) unsigned int*)g,
                                     (__attribute__((address_space(3))) unsigned int*)l,
                                     16, 0, 0);
}

// ---------------- weight transpose+cast: Wt[z][n][k] = W_z[k][n] ----------------
__global__ void wt_kernel(const float* __restrict__ W0, const float* __restrict__ W1,
                          const float* __restrict__ W2, const float* __restrict__ W3,
                          const float* __restrict__ W4, const float* __restrict__ W5,
                          bf16_t* __restrict__ Wt)
{
    __shared__ float tile[32][33];
    const float* W;
    switch (blockIdx.z) {
        case 0: W = W0; break; case 1: W = W1; break; case 2: W = W2; break;
        case 3: W = W3; break; case 4: W = W4; break; default: W = W5; break;
    }
    const int tx = threadIdx.x, ty = threadIdx.y;
    const int n0 = blockIdx.x * 32, k0 = blockIdx.y * 32;
    #pragma unroll
    for (int r = 0; r < 4; ++r)
        tile[ty + 8*r][tx] = W[(size_t)(k0 + ty + 8*r) * DIM + n0 + tx];
    __syncthreads();
    bf16_t* Wtz = Wt + (size_t)blockIdx.z * DIM * DIM;
    #pragma unroll
    for (int r = 0; r < 4; ++r)
        Wtz[(size_t)(n0 + ty + 8*r) * DIM + k0 + tx] = f2bf(tile[tx][ty + 8*r]);
}

// ---------------- fused QKV projection GEMM ----------------
// A[M,512] f32;  Wt[1536][512] bf16 = [Wq^T ; Wk^T ; Wv^T] stacked.
// Outputs: Q[m][n], K[m][n], Vt[b][n][t] (transposed, row stride TKP).
// A staged f32 via global_load_lds with XOR slot swizzle (pre-swizzled source);
// W staged bf16 linear. Double-buffered LDS, one barrier per K-step.
template<int TT, int TKP>
__global__ __launch_bounds__(256, 2)
void proj_fused(const float* __restrict__ A, const bf16_t* __restrict__ Wt,
                const float* __restrict__ bq, const float* __restrict__ bk,
                const float* __restrict__ bv,
                bf16_t* __restrict__ Q, bf16_t* __restrict__ K, bf16_t* __restrict__ Vt)
{
    __shared__ __align__(16) float  a_lds[2][128 * 32];
    __shared__ __align__(16) bf16_t w_lds[2][128 * 32];

    // block decode: same-XCD (stride-8) blocks sweep colt 0..11 at fixed rowt
    const int g = blockIdx.x;
    const int x = g & 7, t = g >> 3;
    const int colt = t % 12;
    const int rowt = (t / 12) * 8 + x;
    const int tid = threadIdx.x;
    const int wv = tid >> 6, lane = tid & 63, l15 = lane & 15, l4 = lane >> 4;
    const int mBase = rowt * 128, nBase = colt * 128;
    const int wr = wv >> 1, wc = wv & 1;

    // A staging: 4 chunks of 32 rows; row = c*32 + (tid>>3), slot = tid&7 (16 B)
    // source col pre-swizzled: slot ^ (row & 7)
    const int arow = tid >> 3, aslot = tid & 7;
    const float* aP[4];
    #pragma unroll
    for (int c = 0; c < 4; ++c) {
        const int r = c * 32 + arow;
        aP[c] = A + (size_t)(mBase + r) * DIM + ((aslot ^ (r & 7)) * 4);
    }
    // W staging: 2 chunks of 64 rows; row = c*64 + (tid>>2), col = (tid&3)*8 bf16
    const bf16_t* wP[2];
    #pragma unroll
    for (int c = 0; c < 2; ++c)
        wP[c] = Wt + (size_t)(nBase + c * 64 + (tid >> 2)) * DIM + (tid & 3) * 8;

    auto stage = [&](int B, int KK) {
        #pragma unroll
        for (int c = 0; c < 4; ++c)
            gload16(aP[c] + KK * 32, &a_lds[B][c * 1024 + tid * 4]);
        #pragma unroll
        for (int c = 0; c < 2; ++c)
            gload16(wP[c] + KK * 32, &w_lds[B][c * 2048 + tid * 8]);
    };

    f32x4 acc[4][4];
    #pragma unroll
    for (int f = 0; f < 4; ++f)
        #pragma unroll
        for (int gg = 0; gg < 4; ++gg) acc[f][gg] = (f32x4){0.f, 0.f, 0.f, 0.f};

    stage(0, 0);
    __syncthreads();                 // drains vmcnt: buf0 ready
    int cur = 0;
    for (int kk = 0; kk < 16; ++kk) {
        if (kk < 15) stage(cur ^ 1, kk + 1);   // prefetch next tile (in flight over compute)

        bf16x8 af[4], bfr[4];
        #pragma unroll
        for (int f = 0; f < 4; ++f) {
            const int row = wr * 64 + f * 16 + l15;
            const float* base = &a_lds[cur][row * 32];
            const int s0 = ((2 * l4)     ^ (row & 7)) * 4;
            const int s1 = ((2 * l4 + 1) ^ (row & 7)) * 4;
            f32x4 lo = *(const f32x4*)(base + s0);
            f32x4 hi = *(const f32x4*)(base + s1);
            #pragma unroll
            for (int u = 0; u < 4; ++u) {
                af[f][u]     = f2bf(lo[u]);
                af[f][4 + u] = f2bf(hi[u]);
            }
        }
        #pragma unroll
        for (int gg = 0; gg < 4; ++gg)
            bfr[gg] = *(const bf16x8*)&w_lds[cur][(wc * 64 + gg * 16 + l15) * 32 + l4 * 8];
        #pragma unroll
        for (int f = 0; f < 4; ++f)
            #pragma unroll
            for (int gg = 0; gg < 4; ++gg)
                acc[f][gg] = __builtin_amdgcn_mfma_f32_16x16x32_bf16(af[f], bfr[gg], acc[f][gg], 0, 0, 0);

        __syncthreads();             // drains prefetch vmcnt + read-done on cur
        cur ^= 1;
    }

    // epilogue
    const int sel = colt >> 2;                  // 0=Q, 1=K, 2=V
    const int nb  = nBase - sel * 512;
    const float* bp = (sel == 0) ? bq : ((sel == 1) ? bk : bv);
    #pragma unroll
    for (int gg = 0; gg < 4; ++gg) {
        const int n = nb + wc * 64 + gg * 16 + l15;
        const float bias_v = bp[n];
        #pragma unroll
        for (int f = 0; f < 4; ++f) {
            #pragma unroll
            for (int i = 0; i < 4; ++i) {
                float v = acc[f][gg][i] + bias_v;
                const int m = mBase + wr * 64 + f * 16 + 4 * l4 + i;
                if (sel == 0) {
                    Q[(size_t)m * DIM + n] = f2bf(v);
                } else if (sel == 1) {
                    K[(size_t)m * DIM + n] = f2bf(v);
                } else {
                    const int bb = m / TT;
                    const int tt = m - bb * TT;
                    Vt[(size_t)bb * DIM * TKP + (size_t)n * TKP + tt] = f2bf(v);
                }
            }
        }
    }
}

// ---------------- e2f attention (Q=eeg 600 rows, K/V=fnirs 120 keys) ----------
__global__ __launch_bounds__(256, 4)
void attn_e2f(const bf16_t* __restrict__ Q, const bf16_t* __restrict__ K,
              const bf16_t* __restrict__ Vt, float* __restrict__ Out)
{
    __shared__ __align__(16) bf16_t p_lds[4][16][104];
    const int b = blockIdx.x, qb = blockIdx.y;
    const int tid = threadIdx.x;
    const int wv = tid >> 6, lane = tid & 63, l15 = lane & 15, l4 = lane >> 4;
    const int qbase = qb * 64 + wv * 16;
    const int K0 = (((qbase / 20) + 20) >> 4) << 4;

    const bf16_t* Qb = Q  + (size_t)b * 600 * DIM;
    const bf16_t* Kb = K  + (size_t)b * 120 * DIM;
    const bf16_t* Vb = Vt + (size_t)b * DIM * 128;

    const int qr = imin(qbase + l15, 599);
    const bf16_t* qp = Qb + (size_t)qr * DIM + l4 * 8;
    bf16x8 q[16];
    #pragma unroll
    for (int c = 0; c < 16; ++c) q[c] = *(const bf16x8*)(qp + c * 32);

    int koffs[5];
    #pragma unroll
    for (int ch = 0; ch < 5; ++ch)
        koffs[ch] = imin(K0 + ch * 16 + l15, 119) * (DIM * 2);
    const char* KbL = (const char*)(Kb + l4 * 8);

    f32x4 acc[5];
    #pragma unroll
    for (int ch = 0; ch < 5; ++ch) acc[ch] = (f32x4){0.f, 0.f, 0.f, 0.f};
    #pragma unroll
    for (int c = 0; c < 16; ++c) {
        #pragma unroll
        for (int ch = 0; ch < 5; ++ch) {
            bf16x8 kf = *(const bf16x8*)(KbL + koffs[ch] + c * 64);
            acc[ch] = __builtin_amdgcn_mfma_f32_16x16x32_bf16(q[c], kf, acc[ch], 0, 0, 0);
        }
    }

    float m[4] = {-INFINITY, -INFINITY, -INFINITY, -INFINITY};
    #pragma unroll
    for (int ch = 0; ch < 5; ++ch) {
        #pragma unroll
        for (int i = 0; i < 4; ++i) {
            const int tq = qbase + 4 * l4 + i;
            const int k = K0 + ch * 16 + l15;
            const int j0 = tq / 20;
            const bool valid = (k < 120) && (k >= j0 + 20) && (k <= j0 + 80);
            float s = valid ? acc[ch][i] * SCALE : -INFINITY;
            acc[ch][i] = s;
            m[i] = fmaxf(m[i], s);
        }
    }
    #pragma unroll
    for (int i = 0; i < 4; ++i) {
        m[i] = fmaxf(m[i], __shfl_xor(m[i], 1, 16));
        m[i] = fmaxf(m[i], __shfl_xor(m[i], 2, 16));
        m[i] = fmaxf(m[i], __shfl_xor(m[i], 4, 16));
        m[i] = fmaxf(m[i], __shfl_xor(m[i], 8, 16));
    }

    float lsum[4] = {0.f, 0.f, 0.f, 0.f};
    #pragma unroll
    for (int ch = 0; ch < 5; ++ch) {
        #pragma unroll
        for (int i = 0; i < 4; ++i) {
            float e = __expf(acc[ch][i] - m[i]);
            lsum[i] += e;
            p_lds[wv][4 * l4 + i][ch * 16 + l15] = f2bf(e);
        }
    }
    #pragma unroll
    for (int i = 0; i < 4; ++i)
        p_lds[wv][4 * l4 + i][80 + l15] = f2bf(0.f);
    #pragma unroll
    for (int i = 0; i < 4; ++i) {
        lsum[i] += __shfl_xor(lsum[i], 1, 16);
        lsum[i] += __shfl_xor(lsum[i], 2, 16);
        lsum[i] += __shfl_xor(lsum[i], 4, 16);
        lsum[i] += __shfl_xor(lsum[i], 8, 16);
        lsum[i] = 1.0f / lsum[i];
    }
    __syncthreads();

    bf16x8 pa[3];
    #pragma unroll
    for (int kt = 0; kt < 3; ++kt)
        pa[kt] = *(const bf16x8*)&p_lds[wv][l15][kt * 32 + l4 * 8];
    int vb[3];
    #pragma unroll
    for (int kt = 0; kt < 3; ++kt) vb[kt] = imin(K0 + kt * 32, 96);

    float* Ob = Out + (size_t)b * 600 * DIM;
    #pragma unroll
    for (int dcg = 0; dcg < 8; ++dcg) {
        f32x4 o[4];
        #pragma unroll
        for (int u = 0; u < 4; ++u) o[u] = (f32x4){0.f, 0.f, 0.f, 0.f};
        #pragma unroll
        for (int u = 0; u < 4; ++u) {
            const bf16_t* vrow = Vb + (size_t)(dcg * 64 + u * 16 + l15) * 128 + l4 * 8;
            #pragma unroll
            for (int kt = 0; kt < 3; ++kt) {
                bf16x8 vf = *(const bf16x8*)(vrow + vb[kt]);
                o[u] = __builtin_amdgcn_mfma_f32_16x16x32_bf16(pa[kt], vf, o[u], 0, 0, 0);
            }
        }
        #pragma unroll
        for (int u = 0; u < 4; ++u) {
            #pragma unroll
            for (int i = 0; i < 4; ++i) {
                const int tq = qbase + 4 * l4 + i;
                if (tq < 600)
                    Ob[(size_t)tq * DIM + (dcg * 4 + u) * 16 + l15] = o[u][i] * lsum[i];
            }
        }
    }
}

// ---------------- f2e attention (Q=fnirs 120 rows, K/V=eeg 600 keys) ----------
// Phase 1: 4 waves split 640 (padded) keys, single-pass scores -> P in LDS.
// Phase 2: d-split — each wave computes all 640 keys x its 128 d-columns.
__global__ __launch_bounds__(256, 3)
void attn_f2e(const bf16_t* __restrict__ Q, const bf16_t* __restrict__ K,
              const bf16_t* __restrict__ Vt, float* __restrict__ Out)
{
    __shared__ __align__(16) bf16_t p_lds[16][648];
    __shared__ float m_lds[4][16];
    __shared__ float l_lds[4][16];

    const int b = blockIdx.x, qt = blockIdx.y;
    const int tid = threadIdx.x;
    const int wv = tid >> 6, lane = tid & 63, l15 = lane & 15, l4 = lane >> 4;
    const int qbase = qt * 16;
    const int koff = wv * 160;

    const bf16_t* Qb = Q  + (size_t)b * 120 * DIM;
    const bf16_t* Kb = K  + (size_t)b * 600 * DIM;
    const bf16_t* Vb = Vt + (size_t)b * DIM * 608;

    const int qr = imin(qbase + l15, 119);
    const bf16_t* qp = Qb + (size_t)qr * DIM + l4 * 8;
    bf16x8 q[16];
    #pragma unroll
    for (int c = 0; c < 16; ++c) q[c] = *(const bf16x8*)(qp + c * 32);

    int koffs[10];
    #pragma unroll
    for (int ch = 0; ch < 10; ++ch)
        koffs[ch] = imin(koff + ch * 16 + l15, 599) * (DIM * 2);
    const char* KbL = (const char*)(Kb + l4 * 8);

    f32x4 acc[10];
    #pragma unroll
    for (int ch = 0; ch < 10; ++ch) acc[ch] = (f32x4){0.f, 0.f, 0.f, 0.f};
    #pragma unroll
    for (int c = 0; c < 16; ++c) {
        #pragma unroll
        for (int ch = 0; ch < 10; ++ch) {
            bf16x8 kf = *(const bf16x8*)(KbL + koffs[ch] + c * 64);
            acc[ch] = __builtin_amdgcn_mfma_f32_16x16x32_bf16(q[c], kf, acc[ch], 0, 0, 0);
        }
    }

    // mask + scale + wave-local max (keys >= 600 -> -inf; real masked -> -1e9)
    float m[4] = {-INFINITY, -INFINITY, -INFINITY, -INFINITY};
    #pragma unroll
    for (int ch = 0; ch < 10; ++ch) {
        #pragma unroll
        for (int i = 0; i < 4; ++i) {
            const int j = qbase + 4 * l4 + i;
            const int k = koff + ch * 16 + l15;
            float s;
            if (k >= 600) {
                s = -INFINITY;
            } else {
                const int j0 = k / 20;
                s = (j >= j0 + 20 && j <= j0 + 80) ? acc[ch][i] * SCALE : -1e9f;
            }
            acc[ch][i] = s;
            m[i] = fmaxf(m[i], s);
        }
    }
    #pragma unroll
    for (int i = 0; i < 4; ++i) {
        m[i] = fmaxf(m[i], __shfl_xor(m[i], 1, 16));
        m[i] = fmaxf(m[i], __shfl_xor(m[i], 2, 16));
        m[i] = fmaxf(m[i], __shfl_xor(m[i], 4, 16));
        m[i] = fmaxf(m[i], __shfl_xor(m[i], 8, 16));
    }
    if (l15 == 0) {
        #pragma unroll
        for (int i = 0; i < 4; ++i) m_lds[wv][4 * l4 + i] = m[i];
    }
    __syncthreads();
    float mg[4];
    #pragma unroll
    for (int i = 0; i < 4; ++i) {
        const int rr = 4 * l4 + i;
        mg[i] = fmaxf(fmaxf(m_lds[0][rr], m_lds[1][rr]), fmaxf(m_lds[2][rr], m_lds[3][rr]));
    }

    float lsum[4] = {0.f, 0.f, 0.f, 0.f};
    #pragma unroll
    for (int ch = 0; ch < 10; ++ch) {
        #pragma unroll
        for (int i = 0; i < 4; ++i) {
            float e = __expf(acc[ch][i] - mg[i]);
            lsum[i] += e;
            p_lds[4 * l4 + i][koff + ch * 16 + l15] = f2bf(e);
        }
    }
    #pragma unroll
    for (int i = 0; i < 4; ++i) {
        lsum[i] += __shfl_xor(lsum[i], 1, 16);
        lsum[i] += __shfl_xor(lsum[i], 2, 16);
        lsum[i] += __shfl_xor(lsum[i], 4, 16);
        lsum[i] += __shfl_xor(lsum[i], 8, 16);
    }
    if (l15 == 0) {
        #pragma unroll
        for (int i = 0; i < 4; ++i) l_lds[wv][4 * l4 + i] = lsum[i];
    }
    __syncthreads();   // P + l published

    // phase 2: this wave owns d-columns [wv*128, wv*128+128)
    float linv[4];
    #pragma unroll
    for (int i = 0; i < 4; ++i) {
        const int rr = 4 * l4 + i;
        linv[i] = 1.0f / (l_lds[0][rr] + l_lds[1][rr] + l_lds[2][rr] + l_lds[3][rr]);
    }

    const int dbase = wv * 128;
    f32x4 o[8];
    #pragma unroll
    for (int u = 0; u < 8; ++u) o[u] = (f32x4){0.f, 0.f, 0.f, 0.f};

    for (int kt = 0; kt < 20; ++kt) {
        bf16x8 pa = *(const bf16x8*)&p_lds[l15][kt * 32 + l4 * 8];
        const int vcol = imin(kt * 32, 576);      // P==0 where clamped
        #pragma unroll
        for (int u = 0; u < 8; ++u) {
            const bf16_t* vp = Vb + (size_t)(dbase + u * 16 + l15) * 608 + vcol + l4 * 8;
            o[u] = __builtin_amdgcn_mfma_f32_16x16x32_bf16(pa, *(const bf16x8*)vp, o[u], 0, 0, 0);
        }
    }

    float* Ob = Out + (size_t)b * 120 * DIM;
    #pragma unroll
    for (int u = 0; u < 8; ++u) {
        #pragma unroll
        for (int i = 0; i < 4; ++i) {
            const int row = qbase + 4 * l4 + i;
            if (row < 120)
                Ob[(size_t)row * DIM + dbase + u * 16 + l15] = o[u][i] * linv[i];
        }
    }
}

// ---------------- host launch ----------------
extern "C" void kernel_launch(void* const* d_in, const int* in_sizes, int n_in,
                              void* d_out, int out_size, void* d_ws, size_t ws_size,
                              hipStream_t stream)
{
    (void)in_sizes; (void)n_in; (void)out_size; (void)ws_size;
    const float* eeg   = (const float*)d_in[0];
    const float* fnirs = (const float*)d_in[1];
    const float* Wqe = (const float*)d_in[2];  const float* bqe = (const float*)d_in[3];
    const float* Wke = (const float*)d_in[4];  const float* bke = (const float*)d_in[5];
    const float* Wve = (const float*)d_in[6];  const float* bve = (const float*)d_in[7];
    const float* Wqf = (const float*)d_in[8];  const float* bqf = (const float*)d_in[9];
    const float* Wkf = (const float*)d_in[10]; const float* bkf = (const float*)d_in[11];
    const float* Wvf = (const float*)d_in[12]; const float* bvf = (const float*)d_in[13];

    char* ws = (char*)d_ws;
    bf16_t* Wt   = (bf16_t*)(ws);                      // 3,145,728 B
    bf16_t* Qe   = (bf16_t*)(ws + 3145728);            // 78,643,200
    bf16_t* Ke   = (bf16_t*)(ws + 81788928);           // 78,643,200
    bf16_t* Qf   = (bf16_t*)(ws + 160432128);          // 15,728,640
    bf16_t* Kf   = (bf16_t*)(ws + 176160768);          // 15,728,640
    bf16_t* Ve_t = (bf16_t*)(ws + 191889408);          // 79,691,776
    bf16_t* Vf_t = (bf16_t*)(ws + 271581184);          // 16,777,216  (total 288,358,400)

    // Wt rows: [Wqe^T; Wke^T; Wve^T; Wqf^T; Wkf^T; Wvf^T]
    wt_kernel<<<dim3(16, 16, 6), dim3(32, 8), 0, stream>>>(Wqe, Wke, Wve, Wqf, Wkf, Wvf, Wt);

    // fused QKV projections (single dispatch per side)
    proj_fused<600, 608><<<7200, 256, 0, stream>>>(eeg, Wt, bqe, bke, bve, Qe, Ke, Ve_t);
    proj_fused<120, 128><<<1440, 256, 0, stream>>>(fnirs, Wt + 3 * 262144, bqf, bkf, bvf, Qf, Kf, Vf_t);

    float* out_eeg   = (float*)d_out;                              // [128][120][512]
    float* out_fnirs = (float*)d_out + (size_t)128 * 120 * 512;    // [128][600][512]

    attn_e2f<<<dim3(128, 10), 256, 0, stream>>>(Qe, Kf, Vf_t, out_fnirs);
    attn_f2e<<<dim3(128, 8),  256, 0, stream>>>(Qf, Ke, Ve_t, out_eeg);
}

// Round 4
// 644.181 us; speedup vs baseline: 1.9981x; 1.0466x over previous
//
#include <hip/hip_runtime.h>
#include <hip/hip_bf16.h>
#include <math.h>

typedef __bf16 bf16_t;
typedef __bf16 bf16x8 __attribute__((ext_vector_type(8)));
typedef __bf16 bf16x4 __attribute__((ext_vector_type(4)));
typedef float f32x4 __attribute__((ext_vector_type(4)));

#define DIM 512
#define SCALE 0.04419417382415922f

static __device__ __forceinline__ bf16_t f2bf(float x) { return (bf16_t)x; }
static __device__ __forceinline__ int imin(int a, int b) { return a < b ? a : b; }

// async global->LDS, 16 B per lane (dest = wave-uniform base + lane*16)
static __device__ __forceinline__ void gload16(const void* g, void* l) {
    __builtin_amdgcn_global_load_lds((const __attribute__((address_space(1))) unsigned int*)g,
                                     (__attribute__((address_space(3))) unsigned int*)l,
                                     16, 0, 0);
}

// ---------------- weight transpose+cast: Wt[z][n][k] = W_z[k][n] ----------------
__global__ void wt_kernel(const float* __restrict__ W0, const float* __restrict__ W1,
                          const float* __restrict__ W2, const float* __restrict__ W3,
                          const float* __restrict__ W4, const float* __restrict__ W5,
                          bf16_t* __restrict__ Wt)
{
    __shared__ float tile[32][33];
    const float* W;
    switch (blockIdx.z) {
        case 0: W = W0; break; case 1: W = W1; break; case 2: W = W2; break;
        case 3: W = W3; break; case 4: W = W4; break; default: W = W5; break;
    }
    const int tx = threadIdx.x, ty = threadIdx.y;
    const int n0 = blockIdx.x * 32, k0 = blockIdx.y * 32;
    #pragma unroll
    for (int r = 0; r < 4; ++r)
        tile[ty + 8*r][tx] = W[(size_t)(k0 + ty + 8*r) * DIM + n0 + tx];
    __syncthreads();
    bf16_t* Wtz = Wt + (size_t)blockIdx.z * DIM * DIM;
    #pragma unroll
    for (int r = 0; r < 4; ++r)
        Wtz[(size_t)(n0 + ty + 8*r) * DIM + k0 + tx] = f2bf(tile[tx][ty + 8*r]);
}

// ---------------- fused QKV projection GEMM ----------------
// A[M,512] f32;  Wt[1536][512] bf16 = [Wq^T ; Wk^T ; Wv^T] stacked.
// Outputs: Q[m][n], K[m][n], Vt[b][n][t] (transposed, row stride TKP).
// Both operands staged via global_load_lds with pre-swizzled SOURCE columns
// (linear LDS dest, swizzled ds_read — rule 21 both-sides involution).
template<int TT, int TKP>
__global__ __launch_bounds__(256, 3)
void proj_fused(const float* __restrict__ A, const bf16_t* __restrict__ Wt,
                const float* __restrict__ bq, const float* __restrict__ bk,
                const float* __restrict__ bv,
                bf16_t* __restrict__ Q, bf16_t* __restrict__ K, bf16_t* __restrict__ Vt)
{
    __shared__ __align__(16) float  a_lds[2][128 * 32];
    __shared__ __align__(16) bf16_t w_lds[2][128 * 32];

    // block decode: same-XCD (stride-8) blocks sweep colt 0..11 at fixed rowt
    const int g = blockIdx.x;
    const int x = g & 7, t = g >> 3;
    const int colt = t % 12;
    const int rowt = (t / 12) * 8 + x;
    const int tid = threadIdx.x;
    const int wv = tid >> 6, lane = tid & 63, l15 = lane & 15, l4 = lane >> 4;
    const int mBase = rowt * 128, nBase = colt * 128;
    const int wr = wv >> 1, wc = wv & 1;

    // A staging: 4 chunks of 32 rows; row = c*32 + (tid>>3), slot = tid&7 (16 B)
    // source slot pre-swizzled: slot ^ (row & 7)
    const int arow = tid >> 3, aslot = tid & 7;
    const float* aP[4];
    #pragma unroll
    for (int c = 0; c < 4; ++c) {
        const int r = c * 32 + arow;
        aP[c] = A + (size_t)(mBase + r) * DIM + ((aslot ^ (r & 7)) * 4);
    }
    // W staging: 2 chunks of 64 rows; row = c*64 + (tid>>2), slot = tid&3 (16 B)
    // source slot pre-swizzled: slot ^ ((row>>1) & 3)
    const bf16_t* wP[2];
    #pragma unroll
    for (int c = 0; c < 2; ++c) {
        const int r = c * 64 + (tid >> 2);
        const int s = (tid & 3) ^ ((r >> 1) & 3);
        wP[c] = Wt + (size_t)(nBase + r) * DIM + s * 8;
    }

    auto stage = [&](int B, int KK) {
        #pragma unroll
        for (int c = 0; c < 4; ++c)
            gload16(aP[c] + KK * 32, &a_lds[B][c * 1024 + tid * 4]);
        #pragma unroll
        for (int c = 0; c < 2; ++c)
            gload16(wP[c] + KK * 32, &w_lds[B][c * 2048 + tid * 8]);
    };

    f32x4 acc[4][4];
    #pragma unroll
    for (int f = 0; f < 4; ++f)
        #pragma unroll
        for (int gg = 0; gg < 4; ++gg) acc[f][gg] = (f32x4){0.f, 0.f, 0.f, 0.f};

    stage(0, 0);
    __syncthreads();                 // drains vmcnt: buf0 ready
    int cur = 0;
    for (int kk = 0; kk < 16; ++kk) {
        if (kk < 15) stage(cur ^ 1, kk + 1);   // prefetch next tile

        bf16x8 af[4], bfr[4];
        #pragma unroll
        for (int f = 0; f < 4; ++f) {
            const int row = wr * 64 + f * 16 + l15;
            const float* base = &a_lds[cur][row * 32];
            const int s0 = ((2 * l4)     ^ (row & 7)) * 4;
            const int s1 = ((2 * l4 + 1) ^ (row & 7)) * 4;
            f32x4 lo = *(const f32x4*)(base + s0);
            f32x4 hi = *(const f32x4*)(base + s1);
            #pragma unroll
            for (int u = 0; u < 4; ++u) {
                af[f][u]     = f2bf(lo[u]);
                af[f][4 + u] = f2bf(hi[u]);
            }
        }
        #pragma unroll
        for (int gg = 0; gg < 4; ++gg) {
            const int row = wc * 64 + gg * 16 + l15;
            bfr[gg] = *(const bf16x8*)&w_lds[cur][row * 32 + (l4 ^ ((row >> 1) & 3)) * 8];
        }
        #pragma unroll
        for (int f = 0; f < 4; ++f)
            #pragma unroll
            for (int gg = 0; gg < 4; ++gg)
                acc[f][gg] = __builtin_amdgcn_mfma_f32_16x16x32_bf16(af[f], bfr[gg], acc[f][gg], 0, 0, 0);

        __syncthreads();             // releases cur, completes prefetch
        cur ^= 1;
    }

    // ---------------- transposed epilogue through LDS ----------------
    bf16_t* cst = (bf16_t*)&a_lds[0][0];        // 128x128 bf16 = 32 KB overlay
    const int sel = colt >> 2;                  // 0=Q, 1=K, 2=V
    const int nb  = nBase - sel * 512;
    const float* bp = (sel == 0) ? bq : ((sel == 1) ? bk : bv);

    if (sel < 2) {
        // cst[m_local][n_local]
        #pragma unroll
        for (int gg = 0; gg < 4; ++gg) {
            const int ncol = wc * 64 + gg * 16 + l15;
            const float bias_v = bp[nb + ncol];
            #pragma unroll
            for (int f = 0; f < 4; ++f)
                #pragma unroll
                for (int i = 0; i < 4; ++i)
                    cst[(wr * 64 + f * 16 + 4 * l4 + i) * 128 + ncol] = f2bf(acc[f][gg][i] + bias_v);
        }
        __syncthreads();
        bf16_t* Cout = (sel == 0) ? Q : K;
        #pragma unroll
        for (int rr = 0; rr < 4; ++rr) {
            const int r  = rr * 32 + (tid >> 3);
            const int c0 = (tid & 7) * 16;
            bf16x8 v0 = *(const bf16x8*)&cst[r * 128 + c0];
            bf16x8 v1 = *(const bf16x8*)&cst[r * 128 + c0 + 8];
            bf16_t* dst = Cout + (size_t)(mBase + r) * DIM + nb + c0;
            *(bf16x8*)dst       = v0;
            *(bf16x8*)(dst + 8) = v1;
        }
    } else {
        // cst[n_local][m_local]; lane packs 4 consecutive m (i-loop) as bf16x4
        #pragma unroll
        for (int gg = 0; gg < 4; ++gg) {
            const int ncol = wc * 64 + gg * 16 + l15;
            const float bias_v = bp[nb + ncol];
            #pragma unroll
            for (int f = 0; f < 4; ++f) {
                bf16x4 pk;
                #pragma unroll
                for (int i = 0; i < 4; ++i) pk[i] = f2bf(acc[f][gg][i] + bias_v);
                *(bf16x4*)&cst[ncol * 128 + wr * 64 + f * 16 + 4 * l4] = pk;
            }
        }
        __syncthreads();
        #pragma unroll
        for (int rr = 0; rr < 4; ++rr) {
            const int nl = rr * 32 + (tid >> 3);
            const int m0 = (tid & 7) * 16;
            const int n  = nb + nl;
            const int mg0 = mBase + m0;
            const int bb0 = mg0 / TT, tt0 = mg0 - bb0 * TT;
            if (tt0 + 15 < TT) {
                // within one batch; tt0 % 8 == 0 -> 8-B aligned vector stores
                bf16_t* dst = Vt + (size_t)bb0 * DIM * TKP + (size_t)n * TKP + tt0;
                #pragma unroll
                for (int u = 0; u < 4; ++u)
                    *(bf16x4*)(dst + u * 4) = *(const bf16x4*)&cst[nl * 128 + m0 + u * 4];
            } else {
                #pragma unroll
                for (int u = 0; u < 16; ++u) {
                    const int mg = mg0 + u;
                    const int bb = mg / TT, tt = mg - bb * TT;
                    Vt[(size_t)bb * DIM * TKP + (size_t)n * TKP + tt] = cst[nl * 128 + m0 + u];
                }
            }
        }
    }
}

// ---------------- e2f attention (Q=eeg 600 rows, K/V=fnirs 120 keys) ----------
__global__ __launch_bounds__(256, 4)
void attn_e2f(const bf16_t* __restrict__ Q, const bf16_t* __restrict__ K,
              const bf16_t* __restrict__ Vt, float* __restrict__ Out)
{
    __shared__ __align__(16) bf16_t p_lds[4][16][104];
    const int b = blockIdx.x, qb = blockIdx.y;
    const int tid = threadIdx.x;
    const int wv = tid >> 6, lane = tid & 63, l15 = lane & 15, l4 = lane >> 4;
    const int qbase = qb * 64 + wv * 16;
    const int K0 = (((qbase / 20) + 20) >> 4) << 4;

    const bf16_t* Qb = Q  + (size_t)b * 600 * DIM;
    const bf16_t* Kb = K  + (size_t)b * 120 * DIM;
    const bf16_t* Vb = Vt + (size_t)b * DIM * 128;

    const int qr = imin(qbase + l15, 599);
    const bf16_t* qp = Qb + (size_t)qr * DIM + l4 * 8;
    bf16x8 q[16];
    #pragma unroll
    for (int c = 0; c < 16; ++c) q[c] = *(const bf16x8*)(qp + c * 32);

    int koffs[5];
    #pragma unroll
    for (int ch = 0; ch < 5; ++ch)
        koffs[ch] = imin(K0 + ch * 16 + l15, 119) * (DIM * 2);
    const char* KbL = (const char*)(Kb + l4 * 8);

    f32x4 acc[5];
    #pragma unroll
    for (int ch = 0; ch < 5; ++ch) acc[ch] = (f32x4){0.f, 0.f, 0.f, 0.f};
    #pragma unroll
    for (int c = 0; c < 16; ++c) {
        #pragma unroll
        for (int ch = 0; ch < 5; ++ch) {
            bf16x8 kf = *(const bf16x8*)(KbL + koffs[ch] + c * 64);
            acc[ch] = __builtin_amdgcn_mfma_f32_16x16x32_bf16(q[c], kf, acc[ch], 0, 0, 0);
        }
    }

    float m[4] = {-INFINITY, -INFINITY, -INFINITY, -INFINITY};
    #pragma unroll
    for (int ch = 0; ch < 5; ++ch) {
        #pragma unroll
        for (int i = 0; i < 4; ++i) {
            const int tq = qbase + 4 * l4 + i;
            const int k = K0 + ch * 16 + l15;
            const int j0 = tq / 20;
            const bool valid = (k < 120) && (k >= j0 + 20) && (k <= j0 + 80);
            float s = valid ? acc[ch][i] * SCALE : -INFINITY;
            acc[ch][i] = s;
            m[i] = fmaxf(m[i], s);
        }
    }
    #pragma unroll
    for (int i = 0; i < 4; ++i) {
        m[i] = fmaxf(m[i], __shfl_xor(m[i], 1, 16));
        m[i] = fmaxf(m[i], __shfl_xor(m[i], 2, 16));
        m[i] = fmaxf(m[i], __shfl_xor(m[i], 4, 16));
        m[i] = fmaxf(m[i], __shfl_xor(m[i], 8, 16));
    }

    float lsum[4] = {0.f, 0.f, 0.f, 0.f};
    #pragma unroll
    for (int ch = 0; ch < 5; ++ch) {
        #pragma unroll
        for (int i = 0; i < 4; ++i) {
            float e = __expf(acc[ch][i] - m[i]);
            lsum[i] += e;
            p_lds[wv][4 * l4 + i][ch * 16 + l15] = f2bf(e);
        }
    }
    #pragma unroll
    for (int i = 0; i < 4; ++i)
        p_lds[wv][4 * l4 + i][80 + l15] = f2bf(0.f);
    #pragma unroll
    for (int i = 0; i < 4; ++i) {
        lsum[i] += __shfl_xor(lsum[i], 1, 16);
        lsum[i] += __shfl_xor(lsum[i], 2, 16);
        lsum[i] += __shfl_xor(lsum[i], 4, 16);
        lsum[i] += __shfl_xor(lsum[i], 8, 16);
        lsum[i] = 1.0f / lsum[i];
    }
    __syncthreads();

    bf16x8 pa[3];
    #pragma unroll
    for (int kt = 0; kt < 3; ++kt)
        pa[kt] = *(const bf16x8*)&p_lds[wv][l15][kt * 32 + l4 * 8];
    int vb[3];
    #pragma unroll
    for (int kt = 0; kt < 3; ++kt) vb[kt] = imin(K0 + kt * 32, 96);

    float* Ob = Out + (size_t)b * 600 * DIM;
    #pragma unroll
    for (int dcg = 0; dcg < 8; ++dcg) {
        f32x4 o[4];
        #pragma unroll
        for (int u = 0; u < 4; ++u) o[u] = (f32x4){0.f, 0.f, 0.f, 0.f};
        #pragma unroll
        for (int u = 0; u < 4; ++u) {
            const bf16_t* vrow = Vb + (size_t)(dcg * 64 + u * 16 + l15) * 128 + l4 * 8;
            #pragma unroll
            for (int kt = 0; kt < 3; ++kt) {
                bf16x8 vf = *(const bf16x8*)(vrow + vb[kt]);
                o[u] = __builtin_amdgcn_mfma_f32_16x16x32_bf16(pa[kt], vf, o[u], 0, 0, 0);
            }
        }
        #pragma unroll
        for (int u = 0; u < 4; ++u) {
            #pragma unroll
            for (int i = 0; i < 4; ++i) {
                const int tq = qbase + 4 * l4 + i;
                if (tq < 600)
                    Ob[(size_t)tq * DIM + (dcg * 4 + u) * 16 + l15] = o[u][i] * lsum[i];
            }
        }
    }
}

// ---------------- f2e attention (Q=fnirs 120 rows, K/V=eeg 600 keys) ----------
// Phase 1: 4 waves split 640 (padded) keys, single-pass scores -> P in LDS.
// Phase 2: d-split — each wave computes all 640 keys x its 128 d-columns.
__global__ __launch_bounds__(256, 3)
void attn_f2e(const bf16_t* __restrict__ Q, const bf16_t* __restrict__ K,
              const bf16_t* __restrict__ Vt, float* __restrict__ Out)
{
    __shared__ __align__(16) bf16_t p_lds[16][648];
    __shared__ float m_lds[4][16];
    __shared__ float l_lds[4][16];

    const int b = blockIdx.x, qt = blockIdx.y;
    const int tid = threadIdx.x;
    const int wv = tid >> 6, lane = tid & 63, l15 = lane & 15, l4 = lane >> 4;
    const int qbase = qt * 16;
    const int koff = wv * 160;

    const bf16_t* Qb = Q  + (size_t)b * 120 * DIM;
    const bf16_t* Kb = K  + (size_t)b * 600 * DIM;
    const bf16_t* Vb = Vt + (size_t)b * DIM * 608;

    const int qr = imin(qbase + l15, 119);
    const bf16_t* qp = Qb + (size_t)qr * DIM + l4 * 8;
    bf16x8 q[16];
    #pragma unroll
    for (int c = 0; c < 16; ++c) q[c] = *(const bf16x8*)(qp + c * 32);

    int koffs[10];
    #pragma unroll
    for (int ch = 0; ch < 10; ++ch)
        koffs[ch] = imin(koff + ch * 16 + l15, 599) * (DIM * 2);
    const char* KbL = (const char*)(Kb + l4 * 8);

    f32x4 acc[10];
    #pragma unroll
    for (int ch = 0; ch < 10; ++ch) acc[ch] = (f32x4){0.f, 0.f, 0.f, 0.f};
    #pragma unroll
    for (int c = 0; c < 16; ++c) {
        #pragma unroll
        for (int ch = 0; ch < 10; ++ch) {
            bf16x8 kf = *(const bf16x8*)(KbL + koffs[ch] + c * 64);
            acc[ch] = __builtin_amdgcn_mfma_f32_16x16x32_bf16(q[c], kf, acc[ch], 0, 0, 0);
        }
    }

    // mask + scale + wave-local max (keys >= 600 -> -inf; real masked -> -1e9)
    float m[4] = {-INFINITY, -INFINITY, -INFINITY, -INFINITY};
    #pragma unroll
    for (int ch = 0; ch < 10; ++ch) {
        #pragma unroll
        for (int i = 0; i < 4; ++i) {
            const int j = qbase + 4 * l4 + i;
            const int k = koff + ch * 16 + l15;
            float s;
            if (k >= 600) {
                s = -INFINITY;
            } else {
                const int j0 = k / 20;
                s = (j >= j0 + 20 && j <= j0 + 80) ? acc[ch][i] * SCALE : -1e9f;
            }
            acc[ch][i] = s;
            m[i] = fmaxf(m[i], s);
        }
    }
    #pragma unroll
    for (int i = 0; i < 4; ++i) {
        m[i] = fmaxf(m[i], __shfl_xor(m[i], 1, 16));
        m[i] = fmaxf(m[i], __shfl_xor(m[i], 2, 16));
        m[i] = fmaxf(m[i], __shfl_xor(m[i], 4, 16));
        m[i] = fmaxf(m[i], __shfl_xor(m[i], 8, 16));
    }
    if (l15 == 0) {
        #pragma unroll
        for (int i = 0; i < 4; ++i) m_lds[wv][4 * l4 + i] = m[i];
    }
    __syncthreads();
    float mg[4];
    #pragma unroll
    for (int i = 0; i < 4; ++i) {
        const int rr = 4 * l4 + i;
        mg[i] = fmaxf(fmaxf(m_lds[0][rr], m_lds[1][rr]), fmaxf(m_lds[2][rr], m_lds[3][rr]));
    }

    float lsum[4] = {0.f, 0.f, 0.f, 0.f};
    #pragma unroll
    for (int ch = 0; ch < 10; ++ch) {
        #pragma unroll
        for (int i = 0; i < 4; ++i) {
            float e = __expf(acc[ch][i] - mg[i]);
            lsum[i] += e;
            p_lds[4 * l4 + i][koff + ch * 16 + l15] = f2bf(e);
        }
    }
    #pragma unroll
    for (int i = 0; i < 4; ++i) {
        lsum[i] += __shfl_xor(lsum[i], 1, 16);
        lsum[i] += __shfl_xor(lsum[i], 2, 16);
        lsum[i] += __shfl_xor(lsum[i], 4, 16);
        lsum[i] += __shfl_xor(lsum[i], 8, 16);
    }
    if (l15 == 0) {
        #pragma unroll
        for (int i = 0; i < 4; ++i) l_lds[wv][4 * l4 + i] = lsum[i];
    }
    __syncthreads();   // P + l published

    // phase 2: this wave owns d-columns [wv*128, wv*128+128)
    float linv[4];
    #pragma unroll
    for (int i = 0; i < 4; ++i) {
        const int rr = 4 * l4 + i;
        linv[i] = 1.0f / (l_lds[0][rr] + l_lds[1][rr] + l_lds[2][rr] + l_lds[3][rr]);
    }

    const int dbase = wv * 128;
    f32x4 o[8];
    #pragma unroll
    for (int u = 0; u < 8; ++u) o[u] = (f32x4){0.f, 0.f, 0.f, 0.f};

    for (int kt = 0; kt < 20; ++kt) {
        bf16x8 pa = *(const bf16x8*)&p_lds[l15][kt * 32 + l4 * 8];
        const int vcol = imin(kt * 32, 576);      // P==0 where clamped
        #pragma unroll
        for (int u = 0; u < 8; ++u) {
            const bf16_t* vp = Vb + (size_t)(dbase + u * 16 + l15) * 608 + vcol + l4 * 8;
            o[u] = __builtin_amdgcn_mfma_f32_16x16x32_bf16(pa, *(const bf16x8*)vp, o[u], 0, 0, 0);
        }
    }

    float* Ob = Out + (size_t)b * 120 * DIM;
    #pragma unroll
    for (int u = 0; u < 8; ++u) {
        #pragma unroll
        for (int i = 0; i < 4; ++i) {
            const int row = qbase + 4 * l4 + i;
            if (row < 120)
                Ob[(size_t)row * DIM + dbase + u * 16 + l15] = o[u][i] * linv[i];
        }
    }
}

// ---------------- host launch ----------------
extern "C" void kernel_launch(void* const* d_in, const int* in_sizes, int n_in,
                              void* d_out, int out_size, void* d_ws, size_t ws_size,
                              hipStream_t stream)
{
    (void)in_sizes; (void)n_in; (void)out_size; (void)ws_size;
    const float* eeg   = (const float*)d_in[0];
    const float* fnirs = (const float*)d_in[1];
    const float* Wqe = (const float*)d_in[2];  const float* bqe = (const float*)d_in[3];
    const float* Wke = (const float*)d_in[4];  const float* bke = (const float*)d_in[5];
    const float* Wve = (const float*)d_in[6];  const float* bve = (const float*)d_in[7];
    const float* Wqf = (const float*)d_in[8];  const float* bqf = (const float*)d_in[9];
    const float* Wkf = (const float*)d_in[10]; const float* bkf = (const float*)d_in[11];
    const float* Wvf = (const float*)d_in[12]; const float* bvf = (const float*)d_in[13];

    char* ws = (char*)d_ws;
    bf16_t* Wt   = (bf16_t*)(ws);                      // 3,145,728 B
    bf16_t* Qe   = (bf16_t*)(ws + 3145728);            // 78,643,200
    bf16_t* Ke   = (bf16_t*)(ws + 81788928);           // 78,643,200
    bf16_t* Qf   = (bf16_t*)(ws + 160432128);          // 15,728,640
    bf16_t* Kf   = (bf16_t*)(ws + 176160768);          // 15,728,640
    bf16_t* Ve_t = (bf16_t*)(ws + 191889408);          // 79,691,776
    bf16_t* Vf_t = (bf16_t*)(ws + 271581184);          // 16,777,216  (total 288,358,400)

    // Wt rows: [Wqe^T; Wke^T; Wve^T; Wqf^T; Wkf^T; Wvf^T]
    wt_kernel<<<dim3(16, 16, 6), dim3(32, 8), 0, stream>>>(Wqe, Wke, Wve, Wqf, Wkf, Wvf, Wt);

    // fused QKV projections (single dispatch per side)
    proj_fused<600, 608><<<7200, 256, 0, stream>>>(eeg, Wt, bqe, bke, bve, Qe, Ke, Ve_t);
    proj_fused<120, 128><<<1440, 256, 0, stream>>>(fnirs, Wt + 3 * 262144, bqf, bkf, bvf, Qf, Kf, Vf_t);

    float* out_eeg   = (float*)d_out;                              // [128][120][512]
    float* out_fnirs = (float*)d_out + (size_t)128 * 120 * 512;    // [128][600][512]

    attn_e2f<<<dim3(128, 10), 256, 0, stream>>>(Qe, Kf, Vf_t, out_fnirs);
    attn_f2e<<<dim3(128, 8),  256, 0, stream>>>(Qf, Ke, Ve_t, out_eeg);
}